// Round 5
// baseline (448.469 us; speedup 1.0000x reference)
//
#include <hip/hip_runtime.h>
#include <math.h>

#define PI_F 3.14159265358979f

typedef __attribute__((ext_vector_type(8))) __bf16 bf16x8;
typedef __attribute__((ext_vector_type(4))) float f32x4;

__device__ __forceinline__ unsigned short f2bf_rne(float v) {
  union { float f; unsigned u; } c; c.f = v;
  unsigned u = c.u;
  return (unsigned short)((u + 0x7fffu + ((u >> 16) & 1u)) >> 16);
}
__device__ __forceinline__ float bfbits2f(unsigned short b) {
  union { unsigned u; float f; } c; c.u = ((unsigned)b) << 16; return c.f;
}
__device__ __forceinline__ unsigned pk2(float a, float b) {
  return (unsigned)f2bf_rne(a) | ((unsigned)f2bf_rne(b) << 16);
}

// ===== weight pre-split + pack: w[oc][ic][3][3] -> wpk[pos][oc][q]{hi[8],lo[8]} =====
// 16 u16 (32B) per (pos,oc,q=ic/8): hi of ic..ic+7 then lo of ic..ic+7, 32B-aligned.
__global__ void prep_w(const float* __restrict__ w, unsigned short* __restrict__ wpk) {
  int i = blockIdx.x * 256 + threadIdx.x;
  if (i >= 9 * 192 * 96) return;
  int pos = i / (192 * 96);
  int rem = i - pos * (192 * 96);
  int oc = rem / 96, ic = rem - oc * 96;
  float v = w[(size_t)rem * 9 + pos];
  unsigned short h = f2bf_rne(v);
  unsigned short l = f2bf_rne(v - bfbits2f(h));
  int q = ic >> 3, j = ic & 7;
  size_t base = ((size_t)(pos * 192 + oc) * 12 + q) * 16;
  wpk[base + j] = h;
  wpk[base + 8 + j] = l;
}

// ============ conv 3x3 implicit GEMM, H=2 rows/block, 3 ic-phases of 32 ============
// 512 threads / 8 waves: wave w -> (hw = w>>2, ocg = w&3), acc[3][4] = 48 regs/wave
// (halves unified-file footprint vs acc[2][3][4]=96 -> 3-4 waves/SIMD instead of 2).
#define ICP 40

__global__ __launch_bounds__(512)
void conv_mfma(const float* __restrict__ x, const unsigned short* __restrict__ wpk,
               float* __restrict__ y) {
  __shared__ unsigned short patch[4 * 66 * ICP];
  const int tid  = threadIdx.x;
  const int wave = tid >> 6, lane = tid & 63;
  const int col  = lane & 15, quad = lane >> 4;
  const int ocg  = wave & 3;            // oc group: 48 oc each
  const int hw   = wave >> 2;           // 0/1: which output row of the pair
  const int w0 = blockIdx.x * 64;
  const int h0 = blockIdx.y * 2;        // output rows h0, h0+1
  const int b  = blockIdx.z;
  const float* xb = x + (size_t)b * 96 * 128 * 128;

  f32x4 acc[3][4];
#pragma unroll
  for (int mt = 0; mt < 3; ++mt)
#pragma unroll
    for (int nt = 0; nt < 4; ++nt) acc[mt][nt] = (f32x4)0.f;

  // lane-dependent part of the weight address (u16 units)
  const int wbase = (48 * ocg + col) * 192 + quad * 16;
  const int cg = tid & 15, pg = tid >> 4;   // pg 0..31

  for (int phase = 0; phase < 3; ++phase) {
    const int ic0 = phase * 32;
    if (phase) __syncthreads();             // protect patch before overwrite

    // ---- staging: 64 (ic-pair, r) tasks x 16 col-groups over 512 threads
#pragma unroll
    for (int it = 0; it < 2; ++it) {
      int pairid = it * 32 + pg;            // 0..63
      int r   = pairid & 3;
      int icl = (pairid >> 2) * 2;          // local ic 0..30 even
      int gr  = h0 - 1 + r;
      const float* r0p = xb + (size_t)(ic0 + icl) * 16384 + gr * 128 + w0 + 4 * cg;
      float4 v0 = make_float4(0.f, 0.f, 0.f, 0.f), v1 = v0;
      if ((unsigned)gr < 128u) {
        v0 = *(const float4*)(r0p);
        v1 = *(const float4*)(r0p + 16384);
      }
      unsigned* pb = (unsigned*)&patch[(r * 66 + 1 + 4 * cg) * ICP + icl];
      pb[0]            = pk2(v0.x, v1.x);
      pb[ICP / 2]      = pk2(v0.y, v1.y);
      pb[ICP]          = pk2(v0.z, v1.z);
      pb[3 * ICP / 2]  = pk2(v0.w, v1.w);
    }
    // halo columns: 2 sides x 4 rows x 32 ic = 256 tasks (first 256 threads)
    if (tid < 256) {
      int side = tid & 1, rr = (tid >> 1) & 3, icl = tid >> 3;
      int gr = h0 - 1 + rr;
      int gc = side ? (w0 + 64) : (w0 - 1);
      float v = 0.f;
      if ((unsigned)gr < 128u && (unsigned)gc < 128u)
        v = xb[(size_t)(ic0 + icl) * 16384 + gr * 128 + gc];
      patch[(rr * 66 + (side ? 65 : 0)) * ICP + icl] = f2bf_rne(v);
    }
    __syncthreads();

    // ---- compute: 9 positions, one 32-ic K-chunk each; this wave's row = hw
#pragma unroll
    for (int pos = 0; pos < 9; ++pos) {
      const int dy = pos / 3, dx = pos - 3 * dy;
      bf16x8 ah[3], al[3];
#pragma unroll
      for (int mt = 0; mt < 3; ++mt) {
        const unsigned short* wp_ =
            wpk + wbase + (((pos * 192 + mt * 16) * 12 + phase * 4) * 16);
        ah[mt] = *(const bf16x8*)(wp_);
        al[mt] = *(const bf16x8*)(wp_ + 8);
      }
      bf16x8 bfrag[4];
#pragma unroll
      for (int nt = 0; nt < 4; ++nt)
        bfrag[nt] = *(const bf16x8*)&patch[((dy + hw) * 66 + nt * 16 + col + dx) * ICP + quad * 8];
#pragma unroll
      for (int mt = 0; mt < 3; ++mt)
#pragma unroll
        for (int nt = 0; nt < 4; ++nt) {
          acc[mt][nt] = __builtin_amdgcn_mfma_f32_16x16x32_bf16(ah[mt], bfrag[nt], acc[mt][nt], 0, 0, 0);
          acc[mt][nt] = __builtin_amdgcn_mfma_f32_16x16x32_bf16(al[mt], bfrag[nt], acc[mt][nt], 0, 0, 0);
        }
    }
  }

  // epilogue: r-pairs (0,1)/(2,3) land at adjacent output cols after pixel-shuffle
  float* yb = y + (size_t)b * 48 * 65536;
  const int h = h0 + hw;
#pragma unroll
  for (int mt = 0; mt < 3; ++mt) {
#pragma unroll
    for (int p = 0; p < 2; ++p) {
      int r0 = 2 * p;
      int oc = 48 * ocg + mt * 16 + quad * 4 + r0;   // even
      int cq = oc >> 2, r2 = (oc >> 1) & 1;
      float* orow = yb + ((size_t)cq * 256 + 2 * h + r2) * 256;
#pragma unroll
      for (int nt = 0; nt < 4; ++nt) {
        int w = w0 + nt * 16 + col;
        *(float2*)&orow[2 * w] = make_float2(acc[mt][nt][r0], acc[mt][nt][r0 + 1]);
      }
    }
  }
}

// ============ fallback fp32 conv ============
#define OCB 8
#define ICB 2
#define PSTRIDE 67
__global__ __launch_bounds__(256)
void conv_ps_kernel(const float* __restrict__ x, const float* __restrict__ wgt,
                    float* __restrict__ y) {
  __shared__ float wsh[OCB * 96 * 9];
  __shared__ float patch[ICB * 18 * PSTRIDE];
  const int tid = threadIdx.x;
  const int b = blockIdx.z / 24, ocg = blockIdx.z % 24;
  const int row0 = blockIdx.y * 16, col0 = blockIdx.x * 64;
  const int tx = tid & 15, ty = tid >> 4;
  for (int i = tid; i < OCB * 96 * 9; i += 256) wsh[i] = wgt[ocg * (OCB * 96 * 9) + i];
  float acc[OCB][4];
#pragma unroll
  for (int o = 0; o < OCB; ++o)
#pragma unroll
    for (int p = 0; p < 4; ++p) acc[o][p] = 0.f;
  const float* xb = x + (size_t)b * 96 * 128 * 128;
  for (int ic0 = 0; ic0 < 96; ic0 += ICB) {
    __syncthreads();
    for (int idx = tid; idx < ICB * 18 * 66; idx += 256) {
      int j = idx / (18 * 66), rem = idx - j * (18 * 66);
      int r = rem / 66, c = rem - r * 66;
      int gr = row0 - 1 + r, gc = col0 - 1 + c;
      float v = 0.f;
      if ((unsigned)gr < 128u && (unsigned)gc < 128u)
        v = xb[((size_t)(ic0 + j) * 128 + gr) * 128 + gc];
      patch[j * (18 * PSTRIDE) + r * PSTRIDE + c] = v;
    }
    __syncthreads();
#pragma unroll
    for (int j = 0; j < ICB; ++j) {
      float xr[3][6];
      const float* pp = &patch[j * (18 * PSTRIDE) + ty * PSTRIDE + tx * 4];
#pragma unroll
      for (int dy = 0; dy < 3; ++dy)
#pragma unroll
        for (int dx = 0; dx < 6; ++dx) xr[dy][dx] = pp[dy * PSTRIDE + dx];
#pragma unroll
      for (int o = 0; o < OCB; ++o) {
        const float* wp = &wsh[(o * 96 + ic0 + j) * 9];
#pragma unroll
        for (int p = 0; p < 4; ++p)
          acc[o][p] += wp[0] * xr[0][p] + wp[1] * xr[0][p + 1] + wp[2] * xr[0][p + 2]
                     + wp[3] * xr[1][p] + wp[4] * xr[1][p + 1] + wp[5] * xr[1][p + 2]
                     + wp[6] * xr[2][p] + wp[7] * xr[2][p + 1] + wp[8] * xr[2][p + 2];
      }
    }
  }
  const int h = row0 + ty;
#pragma unroll
  for (int o = 0; o < OCB; ++o) {
    int ocglob = ocg * OCB + o;
    int cq = ocglob >> 2, r2 = (ocglob >> 1) & 1, s2 = ocglob & 1;
    float* orow = y + (((size_t)b * 48 + cq) * 256 + (2 * h + r2)) * 256;
#pragma unroll
    for (int p = 0; p < 4; ++p) orow[2 * (col0 + tx * 4 + p) + s2] = acc[o][p];
  }
}

// ================= wave-synchronous register radix-4 FFT (256 = 4^4) =================
// Forward DIF: k = q + 4*q2 + 16*q3 + 64*q4. Mask k in [64,192) <=> q4 in {1,2}.
__device__ __forceinline__ float2 cadd(float2 a, float2 b){return make_float2(a.x+b.x, a.y+b.y);}
__device__ __forceinline__ float2 csub(float2 a, float2 b){return make_float2(a.x-b.x, a.y-b.y);}
__device__ __forceinline__ float2 cmul(float2 a, float2 b){return make_float2(a.x*b.x-a.y*b.y, a.x*b.y+a.y*b.x);}
__device__ __forceinline__ float2 cmulc(float2 a, float2 b){return make_float2(a.x*b.x+a.y*b.y, a.y*b.x-a.x*b.y);}

__device__ __forceinline__ void dft4(float2 r[4]) {
  float2 e0 = cadd(r[0], r[2]), e1 = csub(r[0], r[2]);
  float2 o0 = cadd(r[1], r[3]), o1 = csub(r[1], r[3]);
  r[0] = cadd(e0, o0);
  r[2] = csub(e0, o0);
  r[1] = make_float2(e1.x + o1.y, e1.y - o1.x);
  r[3] = make_float2(e1.x - o1.y, e1.y + o1.x);
}
__device__ __forceinline__ void idft4(float2 r[4]) {
  float2 e0 = cadd(r[0], r[2]), e1 = csub(r[0], r[2]);
  float2 o0 = cadd(r[1], r[3]), o1 = csub(r[1], r[3]);
  r[0] = cadd(e0, o0);
  r[2] = csub(e0, o0);
  r[1] = make_float2(e1.x - o1.y, e1.y + o1.x);
  r[3] = make_float2(e1.x + o1.y, e1.y - o1.x);
}

struct TwSet {
  float2 f1[3], f2[3], f3[3], i2[4], i3[4];
};

__device__ __forceinline__ void load_tw(TwSet& T, const float2* __restrict__ tw, int l) {
  const int qq = l >> 4, m = l & 15, q2r = (l >> 2) & 3, c2 = l & 3;
  T.f1[0] = tw[l];
  T.f1[1] = tw[(2 * l) & 255];
  T.f1[2] = tw[(3 * l) & 255];
  T.f2[0] = tw[(4 * m) & 255];
  T.f2[1] = tw[(8 * m) & 255];
  T.f2[2] = tw[(12 * m) & 255];
  T.f3[0] = tw[(16 * c2) & 255];
  T.f3[1] = tw[(32 * c2) & 255];
  T.f3[2] = tw[(48 * c2) & 255];
  T.i2[0] = tw[(4 * c2 * q2r) & 255];
  T.i2[1] = tw[(4 * (c2 + 4) * q2r) & 255];
  T.i2[2] = tw[(4 * (c2 + 8) * q2r) & 255];
  T.i2[3] = tw[(4 * (c2 + 12) * q2r) & 255];
  T.i3[0] = tw[(m * qq) & 255];
  T.i3[1] = tw[((m + 16) * qq) & 255];
  T.i3[2] = tw[((m + 32) * qq) & 255];
  T.i3[3] = tw[((m + 48) * qq) & 255];
}

// r[t] in: x[l + 64t]; out: L[l + 64t] (unscaled). S = per-line LDS (element s at S[ST*s]).
template <int ST>
__device__ void fft_line_masked(float2 r[4], float2* __restrict__ S, const TwSet& T, int l) {
  const int qq = l >> 4, m = l & 15;
  const int g = l >> 2, q2r = (l >> 2) & 3, c2 = l & 3;
  // ---- F1 (stride 64) + twiddle w256^(l*q)
  dft4(r);
  r[1] = cmul(r[1], T.f1[0]);
  r[2] = cmul(r[2], T.f1[1]);
  r[3] = cmul(r[3], T.f1[2]);
  S[ST * l] = r[0];
  S[ST * (64 + l)] = r[1];
  S[ST * (128 + l)] = r[2];
  S[ST * (192 + l)] = r[3];
#pragma unroll
  for (int t = 0; t < 4; ++t) r[t] = S[ST * (qq * 64 + m + 16 * t)];
  // ---- F2 (stride 16 within 64) + w64^(m*q2)
  dft4(r);
  r[1] = cmul(r[1], T.f2[0]);
  r[2] = cmul(r[2], T.f2[1]);
  r[3] = cmul(r[3], T.f2[2]);
#pragma unroll
  for (int q2 = 0; q2 < 4; ++q2) S[ST * (qq * 64 + q2 * 16 + ((m + 4 * q2) & 15))] = r[q2];
#pragma unroll
  for (int t = 0; t < 4; ++t) r[t] = S[ST * (qq * 64 + q2r * 16 + ((c2 + 4 * t + 4 * q2r) & 15))];
  // ---- F3 (stride 4 within 16) + w16^(c*q3)
  dft4(r);
  r[1] = cmul(r[1], T.f3[0]);
  r[2] = cmul(r[2], T.f3[1]);
  r[3] = cmul(r[3], T.f3[2]);
#pragma unroll
  for (int q3 = 0; q3 < 4; ++q3) S[ST * (g * 16 + ((4 * q3 + c2 + g) & 15))] = r[q3];
#pragma unroll
  for (int t = 0; t < 4; ++t) r[t] = S[ST * (g * 16 + ((4 * c2 + t + g) & 15))];
  // ---- F4 (final DFT-4) -> regs q4; mask q4 in {1,2}; I1 with 2 nonzero inputs
  dft4(r);
  {
    float2 V0 = r[0], V3 = r[3];
    r[0] = cadd(V0, V3);
    r[1] = make_float2(V0.x + V3.y, V0.y - V3.x);   // V0 + (-i)V3
    r[2] = csub(V0, V3);
    r[3] = make_float2(V0.x - V3.y, V0.y + V3.x);   // V0 + (i)V3
  }
  // undo F3 twiddle (conj), reg index = c, lane q3 = c2
  r[1] = cmulc(r[1], T.f3[0]);
  r[2] = cmulc(r[2], T.f3[1]);
  r[3] = cmulc(r[3], T.f3[2]);
#pragma unroll
  for (int j = 0; j < 4; ++j) S[ST * (g * 16 + ((4 * c2 + j + g) & 15))] = r[j];
#pragma unroll
  for (int t = 0; t < 4; ++t) r[t] = S[ST * (g * 16 + ((4 * t + c2 + g) & 15))];
  // ---- I2 (inverse over q3) -> positions m = c2+4t; undo F2 twiddle
  idft4(r);
  r[0] = cmulc(r[0], T.i2[0]);
  r[1] = cmulc(r[1], T.i2[1]);
  r[2] = cmulc(r[2], T.i2[2]);
  r[3] = cmulc(r[3], T.i2[3]);
#pragma unroll
  for (int t1 = 0; t1 < 4; ++t1) S[ST * (qq * 64 + q2r * 16 + ((c2 + 4 * t1 + 4 * q2r) & 15))] = r[t1];
#pragma unroll
  for (int t = 0; t < 4; ++t) r[t] = S[ST * (qq * 64 + t * 16 + ((m + 4 * t) & 15))];
  // ---- I3 (inverse over q2) -> positions l' = m+16t; undo F1 twiddle
  idft4(r);
  r[0] = cmulc(r[0], T.i3[0]);
  r[1] = cmulc(r[1], T.i3[1]);
  r[2] = cmulc(r[2], T.i3[2]);
  r[3] = cmulc(r[3], T.i3[3]);
#pragma unroll
  for (int t2 = 0; t2 < 4; ++t2) S[ST * (qq * 64 + m + 16 * t2)] = r[t2];
#pragma unroll
  for (int t = 0; t < 4; ++t) r[t] = S[ST * (t * 64 + l)];
  // ---- I4 (inverse over q) -> x[l + 64t]
  idft4(r);
}

// Row pass: 4 lines/block (1 per wave), no barriers in transform
__global__ __launch_bounds__(256)
void fft_rows_kernel(const float* __restrict__ y, float2* __restrict__ z1) {
  __shared__ float2 S[4 * 256];
  __shared__ float2 tw[256];
  const int tid = threadIdx.x;
  {
    float sn, cs;
    __sincosf(-2.f * PI_F * (float)tid / 256.f, &sn, &cs);
    tw[tid] = make_float2(cs, sn);
  }
  __syncthreads();
  const int wv = tid >> 6, l = tid & 63;
  TwSet T;
  load_tw(T, tw, l);
  const size_t rowbase = ((size_t)blockIdx.x * 4 + wv) * 256;
  float2 r[4];
#pragma unroll
  for (int t = 0; t < 4; ++t) r[t] = make_float2(y[rowbase + l + 64 * t], 0.f);
  fft_line_masked<1>(r, S + wv * 256, T, l);
#pragma unroll
  for (int t = 0; t < 4; ++t)
    z1[rowbase + l + 64 * t] = make_float2(r[t].x * (1.f / 256.f), r[t].y * (1.f / 256.f));
}

// Col pass: 16-col strip in LDS (stride 17), in-place FFT per column, 4 cols/wave
#define CST 17
__global__ __launch_bounds__(256)
void fft_cols_kernel(const float2* __restrict__ z1, const float* __restrict__ yy,
                     float* __restrict__ out, const float* __restrict__ betaPtr) {
  __shared__ float2 strip[256 * CST];
  __shared__ float2 tw[256];
  const int tid = threadIdx.x;
  {
    float sn, cs;
    __sincosf(-2.f * PI_F * (float)tid / 256.f, &sn, &cs);
    tw[tid] = make_float2(cs, sn);
  }
  const int img = blockIdx.x >> 4;
  const int c0 = (blockIdx.x & 15) * 16;
  const size_t ibase = (size_t)img * 65536;
#pragma unroll
  for (int it = 0; it < 16; ++it) {
    int idx = it * 256 + tid;
    int rrow = idx >> 4, cc = idx & 15;
    strip[rrow * CST + cc] = z1[ibase + (size_t)rrow * 256 + c0 + cc];
  }
  __syncthreads();
  const int wv = tid >> 6, l = tid & 63;
  TwSet T;
  load_tw(T, tw, l);
  float2 r[4];
#pragma unroll
  for (int ci = 0; ci < 4; ++ci) {
    const int c = wv * 4 + ci;
    float2* Sc = strip + c;
#pragma unroll
    for (int t = 0; t < 4; ++t) r[t] = Sc[CST * (l + 64 * t)];
    fft_line_masked<CST>(r, Sc, T, l);
#pragma unroll
    for (int t = 0; t < 4; ++t) {
      float2 v = r[t];
      Sc[CST * (l + 64 * t)].x = sqrtf(v.x * v.x + v.y * v.y) * (1.f / 256.f);
    }
  }
  __syncthreads();
  const float beta = betaPtr[0];
  const float a1 = 1.f - 2.f * beta;
#pragma unroll
  for (int it = 0; it < 16; ++it) {
    int idx = it * 256 + tid;
    int rrow = idx >> 4, cc = idx & 15;
    size_t gi = ibase + (size_t)rrow * 256 + c0 + cc;
    out[gi] = beta * yy[gi] + a1 * strip[rrow * CST + cc].x;
  }
}

// ================= launch =================
extern "C" void kernel_launch(void* const* d_in, const int* in_sizes, int n_in,
                              void* d_out, int out_size, void* d_ws, size_t ws_size,
                              hipStream_t stream) {
  const float* x = (const float*)d_in[0];
  const float* wgt = (const float*)d_in[1];
  const float* beta = (const float*)d_in[2];
  float* out = (float*)d_out;

  const size_t wplane = (size_t)9 * 192 * 96;
  const size_t wbytes = (2 * wplane * sizeof(unsigned short) + 255) & ~(size_t)255;
  const size_t per_img = 65536ull * sizeof(float2);
  const int NIMG = 8 * 48;

  float2* z1;
  size_t z1_bytes;

  if (ws_size >= wbytes + per_img) {
    unsigned short* wpk = (unsigned short*)d_ws;
    z1 = (float2*)((char*)d_ws + wbytes);
    z1_bytes = ws_size - wbytes;
    prep_w<<<648, 256, 0, stream>>>(wgt, wpk);
    conv_mfma<<<dim3(2, 64, 8), 512, 0, stream>>>(x, wpk, out);
  } else {
    z1 = (float2*)d_ws;
    z1_bytes = ws_size;
    conv_ps_kernel<<<dim3(2, 8, 192), 256, 0, stream>>>(x, wgt, out);
  }

  int chunk = (int)(z1_bytes / per_img);
  if (chunk < 1) chunk = 1;
  if (chunk > NIMG) chunk = NIMG;
  for (int img0 = 0; img0 < NIMG; img0 += chunk) {
    int n = NIMG - img0;
    if (n > chunk) n = chunk;
    float* ych = out + (size_t)img0 * 65536;
    fft_rows_kernel<<<n * 64, 256, 0, stream>>>(ych, z1);
    fft_cols_kernel<<<n * 16, 256, 0, stream>>>(z1, ych, ych, beta);
  }
}

// Round 6
// 385.144 us; speedup vs baseline: 1.1644x; 1.1644x over previous
//
#include <hip/hip_runtime.h>
#include <math.h>

#define PI_F 3.14159265358979f

typedef __attribute__((ext_vector_type(8))) __bf16 bf16x8;
typedef __attribute__((ext_vector_type(4))) float f32x4;

__device__ __forceinline__ unsigned short f2bf_rne(float v) {
  union { float f; unsigned u; } c; c.f = v;
  unsigned u = c.u;
  return (unsigned short)((u + 0x7fffu + ((u >> 16) & 1u)) >> 16);
}
__device__ __forceinline__ float bfbits2f(unsigned short b) {
  union { unsigned u; float f; } c; c.u = ((unsigned)b) << 16; return c.f;
}
__device__ __forceinline__ unsigned pk2(float a, float b) {
  return (unsigned)f2bf_rne(a) | ((unsigned)f2bf_rne(b) << 16);
}

// ===== weight pre-split + pack: w[oc][ic][3][3] -> wpk[pos][oc][q]{hi[8],lo[8]} =====
__global__ void prep_w(const float* __restrict__ w, unsigned short* __restrict__ wpk) {
  int i = blockIdx.x * 256 + threadIdx.x;
  if (i >= 9 * 192 * 96) return;
  int pos = i / (192 * 96);
  int rem = i - pos * (192 * 96);
  int oc = rem / 96, ic = rem - oc * 96;
  float v = w[(size_t)rem * 9 + pos];
  unsigned short h = f2bf_rne(v);
  unsigned short l = f2bf_rne(v - bfbits2f(h));
  int q = ic >> 3, j = ic & 7;
  size_t base = ((size_t)(pos * 192 + oc) * 12 + q) * 16;
  wpk[base + j] = h;
  wpk[base + 8 + j] = l;
}

// ============ conv 3x3 implicit GEMM, H=2 rows/block, 3 ic-phases of 32 ============
// ROUND-4 WINNER (121 us, MfmaUtil 29%): 256 thr / 4 waves, acc[2][3][4]=96 AGPR,
// long 48-MFMA bursts per weight load. Round-5 A/B showed splitting waves 2x
// (shorter bursts, 2x weight-load bursts) regresses despite 2x occupancy.
#define ICP 40

__global__ __launch_bounds__(256)
void conv_mfma(const float* __restrict__ x, const unsigned short* __restrict__ wpk,
               float* __restrict__ y) {
  __shared__ unsigned short patch[4 * 66 * ICP];
  const int tid  = threadIdx.x;
  const int wave = tid >> 6, lane = tid & 63;
  const int col  = lane & 15, quad = lane >> 4;
  const int w0 = blockIdx.x * 64;
  const int h0 = blockIdx.y * 2;                   // output rows h0, h0+1
  const int b  = blockIdx.z;
  const float* xb = x + (size_t)b * 96 * 128 * 128;

  f32x4 acc[2][3][4];
#pragma unroll
  for (int hh = 0; hh < 2; ++hh)
#pragma unroll
    for (int mt = 0; mt < 3; ++mt)
#pragma unroll
      for (int nt = 0; nt < 4; ++nt) acc[hh][mt][nt] = (f32x4)0.f;

  const int wbase = (48 * wave + col) * 192 + quad * 16;
  const int cg = tid & 15, pg = tid >> 4;

  for (int phase = 0; phase < 3; ++phase) {
    const int ic0 = phase * 32;
    if (phase) __syncthreads();

#pragma unroll
    for (int it = 0; it < 4; ++it) {
      int pairid = it * 16 + pg;
      int r   = pairid & 3;
      int icl = (pairid >> 2) * 2;
      int gr  = h0 - 1 + r;
      const float* r0p = xb + (size_t)(ic0 + icl) * 16384 + gr * 128 + w0 + 4 * cg;
      float4 v0 = make_float4(0.f, 0.f, 0.f, 0.f), v1 = v0;
      if ((unsigned)gr < 128u) {
        v0 = *(const float4*)(r0p);
        v1 = *(const float4*)(r0p + 16384);
      }
      unsigned* pb = (unsigned*)&patch[(r * 66 + 1 + 4 * cg) * ICP + icl];
      pb[0]            = pk2(v0.x, v1.x);
      pb[ICP / 2]      = pk2(v0.y, v1.y);
      pb[ICP]          = pk2(v0.z, v1.z);
      pb[3 * ICP / 2]  = pk2(v0.w, v1.w);
    }
    {
      int side = tid & 1, rr = (tid >> 1) & 3, icl = tid >> 3;
      int gr = h0 - 1 + rr;
      int gc = side ? (w0 + 64) : (w0 - 1);
      float v = 0.f;
      if ((unsigned)gr < 128u && (unsigned)gc < 128u)
        v = xb[(size_t)(ic0 + icl) * 16384 + gr * 128 + gc];
      patch[(rr * 66 + (side ? 65 : 0)) * ICP + icl] = f2bf_rne(v);
    }
    __syncthreads();

#pragma unroll
    for (int pos = 0; pos < 9; ++pos) {
      const int dy = pos / 3, dx = pos - 3 * dy;
      bf16x8 ah[3], al[3];
#pragma unroll
      for (int mt = 0; mt < 3; ++mt) {
        const unsigned short* wp_ =
            wpk + wbase + (((pos * 192 + mt * 16) * 12 + phase * 4) * 16);
        ah[mt] = *(const bf16x8*)(wp_);
        al[mt] = *(const bf16x8*)(wp_ + 8);
      }
#pragma unroll
      for (int hh = 0; hh < 2; ++hh) {
        bf16x8 bfrag[4];
#pragma unroll
        for (int nt = 0; nt < 4; ++nt)
          bfrag[nt] = *(const bf16x8*)&patch[((dy + hh) * 66 + nt * 16 + col + dx) * ICP + quad * 8];
#pragma unroll
        for (int mt = 0; mt < 3; ++mt)
#pragma unroll
          for (int nt = 0; nt < 4; ++nt) {
            acc[hh][mt][nt] = __builtin_amdgcn_mfma_f32_16x16x32_bf16(ah[mt], bfrag[nt], acc[hh][mt][nt], 0, 0, 0);
            acc[hh][mt][nt] = __builtin_amdgcn_mfma_f32_16x16x32_bf16(al[mt], bfrag[nt], acc[hh][mt][nt], 0, 0, 0);
          }
      }
    }
  }

  float* yb = y + (size_t)b * 48 * 65536;
#pragma unroll
  for (int hh = 0; hh < 2; ++hh) {
    const int h = h0 + hh;
#pragma unroll
    for (int mt = 0; mt < 3; ++mt) {
#pragma unroll
      for (int p = 0; p < 2; ++p) {
        int r0 = 2 * p;
        int oc = 48 * wave + mt * 16 + quad * 4 + r0;
        int cq = oc >> 2, r2 = (oc >> 1) & 1;
        float* orow = yb + ((size_t)cq * 256 + 2 * h + r2) * 256;
#pragma unroll
        for (int nt = 0; nt < 4; ++nt) {
          int w = w0 + nt * 16 + col;
          *(float2*)&orow[2 * w] = make_float2(acc[hh][mt][nt][r0], acc[hh][mt][nt][r0 + 1]);
        }
      }
    }
  }
}

// ============ fallback fp32 conv ============
#define OCB 8
#define ICB 2
#define PSTRIDE 67
__global__ __launch_bounds__(256)
void conv_ps_kernel(const float* __restrict__ x, const float* __restrict__ wgt,
                    float* __restrict__ y) {
  __shared__ float wsh[OCB * 96 * 9];
  __shared__ float patch[ICB * 18 * PSTRIDE];
  const int tid = threadIdx.x;
  const int b = blockIdx.z / 24, ocg = blockIdx.z % 24;
  const int row0 = blockIdx.y * 16, col0 = blockIdx.x * 64;
  const int tx = tid & 15, ty = tid >> 4;
  for (int i = tid; i < OCB * 96 * 9; i += 256) wsh[i] = wgt[ocg * (OCB * 96 * 9) + i];
  float acc[OCB][4];
#pragma unroll
  for (int o = 0; o < OCB; ++o)
#pragma unroll
    for (int p = 0; p < 4; ++p) acc[o][p] = 0.f;
  const float* xb = x + (size_t)b * 96 * 128 * 128;
  for (int ic0 = 0; ic0 < 96; ic0 += ICB) {
    __syncthreads();
    for (int idx = tid; idx < ICB * 18 * 66; idx += 256) {
      int j = idx / (18 * 66), rem = idx - j * (18 * 66);
      int r = rem / 66, c = rem - r * 66;
      int gr = row0 - 1 + r, gc = col0 - 1 + c;
      float v = 0.f;
      if ((unsigned)gr < 128u && (unsigned)gc < 128u)
        v = xb[((size_t)(ic0 + j) * 128 + gr) * 128 + gc];
      patch[j * (18 * PSTRIDE) + r * PSTRIDE + c] = v;
    }
    __syncthreads();
#pragma unroll
    for (int j = 0; j < ICB; ++j) {
      float xr[3][6];
      const float* pp = &patch[j * (18 * PSTRIDE) + ty * PSTRIDE + tx * 4];
#pragma unroll
      for (int dy = 0; dy < 3; ++dy)
#pragma unroll
        for (int dx = 0; dx < 6; ++dx) xr[dy][dx] = pp[dy * PSTRIDE + dx];
#pragma unroll
      for (int o = 0; o < OCB; ++o) {
        const float* wp = &wsh[(o * 96 + ic0 + j) * 9];
#pragma unroll
        for (int p = 0; p < 4; ++p)
          acc[o][p] += wp[0] * xr[0][p] + wp[1] * xr[0][p + 1] + wp[2] * xr[0][p + 2]
                     + wp[3] * xr[1][p] + wp[4] * xr[1][p + 1] + wp[5] * xr[1][p + 2]
                     + wp[6] * xr[2][p] + wp[7] * xr[2][p + 1] + wp[8] * xr[2][p + 2];
      }
    }
  }
  const int h = row0 + ty;
#pragma unroll
  for (int o = 0; o < OCB; ++o) {
    int ocglob = ocg * OCB + o;
    int cq = ocglob >> 2, r2 = (ocglob >> 1) & 1, s2 = ocglob & 1;
    float* orow = y + (((size_t)b * 48 + cq) * 256 + (2 * h + r2)) * 256;
#pragma unroll
    for (int p = 0; p < 4; ++p) orow[2 * (col0 + tx * 4 + p) + s2] = acc[o][p];
  }
}

// ================= wave-synchronous register radix-4 FFT (256 = 4^4) =================
// 2-WIDE: each wave processes TWO independent lines; every stage issues line-B's
// LDS ops while line-A's are in flight -> exposed ds latency ~halves. Same math,
// same op order per line as the verified 1-wide version.
__device__ __forceinline__ float2 cadd(float2 a, float2 b){return make_float2(a.x+b.x, a.y+b.y);}
__device__ __forceinline__ float2 csub(float2 a, float2 b){return make_float2(a.x-b.x, a.y-b.y);}
__device__ __forceinline__ float2 cmul(float2 a, float2 b){return make_float2(a.x*b.x-a.y*b.y, a.x*b.y+a.y*b.x);}
__device__ __forceinline__ float2 cmulc(float2 a, float2 b){return make_float2(a.x*b.x+a.y*b.y, a.y*b.x-a.x*b.y);}

__device__ __forceinline__ void dft4(float2 r[4]) {
  float2 e0 = cadd(r[0], r[2]), e1 = csub(r[0], r[2]);
  float2 o0 = cadd(r[1], r[3]), o1 = csub(r[1], r[3]);
  r[0] = cadd(e0, o0);
  r[2] = csub(e0, o0);
  r[1] = make_float2(e1.x + o1.y, e1.y - o1.x);
  r[3] = make_float2(e1.x - o1.y, e1.y + o1.x);
}
__device__ __forceinline__ void idft4(float2 r[4]) {
  float2 e0 = cadd(r[0], r[2]), e1 = csub(r[0], r[2]);
  float2 o0 = cadd(r[1], r[3]), o1 = csub(r[1], r[3]);
  r[0] = cadd(e0, o0);
  r[2] = csub(e0, o0);
  r[1] = make_float2(e1.x - o1.y, e1.y + o1.x);
  r[3] = make_float2(e1.x + o1.y, e1.y - o1.x);
}

struct TwSet {
  float2 f1[3], f2[3], f3[3], i2[4], i3[4];
};

__device__ __forceinline__ void load_tw(TwSet& T, const float2* __restrict__ tw, int l) {
  const int qq = l >> 4, m = l & 15, q2r = (l >> 2) & 3, c2 = l & 3;
  T.f1[0] = tw[l];
  T.f1[1] = tw[(2 * l) & 255];
  T.f1[2] = tw[(3 * l) & 255];
  T.f2[0] = tw[(4 * m) & 255];
  T.f2[1] = tw[(8 * m) & 255];
  T.f2[2] = tw[(12 * m) & 255];
  T.f3[0] = tw[(16 * c2) & 255];
  T.f3[1] = tw[(32 * c2) & 255];
  T.f3[2] = tw[(48 * c2) & 255];
  T.i2[0] = tw[(4 * c2 * q2r) & 255];
  T.i2[1] = tw[(4 * (c2 + 4) * q2r) & 255];
  T.i2[2] = tw[(4 * (c2 + 8) * q2r) & 255];
  T.i2[3] = tw[(4 * (c2 + 12) * q2r) & 255];
  T.i3[0] = tw[(m * qq) & 255];
  T.i3[1] = tw[((m + 16) * qq) & 255];
  T.i3[2] = tw[((m + 32) * qq) & 255];
  T.i3[3] = tw[((m + 48) * qq) & 255];
}

// Two lines per wave. r[u][t] in: x_u[l + 64t]; out: filtered x_u[l + 64t] (unscaled).
// S[u] = per-line LDS slice (element s at S[u][ST*s]). Slices must be disjoint.
template <int ST>
__device__ void fft_line2(float2 r[2][4], float2* __restrict__ S0, float2* __restrict__ S1,
                          const TwSet& T, int l) {
  float2* S[2] = { S0, S1 };
  const int qq = l >> 4, m = l & 15;
  const int g = l >> 2, q2r = (l >> 2) & 3, c2 = l & 3;
  // ---- F1 (stride 64) + twiddle w256^(l*q)
#pragma unroll
  for (int u = 0; u < 2; ++u) {
    dft4(r[u]);
    r[u][1] = cmul(r[u][1], T.f1[0]);
    r[u][2] = cmul(r[u][2], T.f1[1]);
    r[u][3] = cmul(r[u][3], T.f1[2]);
  }
#pragma unroll
  for (int u = 0; u < 2; ++u) {
    S[u][ST * l] = r[u][0];
    S[u][ST * (64 + l)] = r[u][1];
    S[u][ST * (128 + l)] = r[u][2];
    S[u][ST * (192 + l)] = r[u][3];
  }
#pragma unroll
  for (int u = 0; u < 2; ++u)
#pragma unroll
    for (int t = 0; t < 4; ++t) r[u][t] = S[u][ST * (qq * 64 + m + 16 * t)];
  // ---- F2 (stride 16 within 64) + w64^(m*q2)
#pragma unroll
  for (int u = 0; u < 2; ++u) {
    dft4(r[u]);
    r[u][1] = cmul(r[u][1], T.f2[0]);
    r[u][2] = cmul(r[u][2], T.f2[1]);
    r[u][3] = cmul(r[u][3], T.f2[2]);
  }
#pragma unroll
  for (int u = 0; u < 2; ++u)
#pragma unroll
    for (int q2 = 0; q2 < 4; ++q2) S[u][ST * (qq * 64 + q2 * 16 + ((m + 4 * q2) & 15))] = r[u][q2];
#pragma unroll
  for (int u = 0; u < 2; ++u)
#pragma unroll
    for (int t = 0; t < 4; ++t) r[u][t] = S[u][ST * (qq * 64 + q2r * 16 + ((c2 + 4 * t + 4 * q2r) & 15))];
  // ---- F3 (stride 4 within 16) + w16^(c*q3)
#pragma unroll
  for (int u = 0; u < 2; ++u) {
    dft4(r[u]);
    r[u][1] = cmul(r[u][1], T.f3[0]);
    r[u][2] = cmul(r[u][2], T.f3[1]);
    r[u][3] = cmul(r[u][3], T.f3[2]);
  }
#pragma unroll
  for (int u = 0; u < 2; ++u)
#pragma unroll
    for (int q3 = 0; q3 < 4; ++q3) S[u][ST * (g * 16 + ((4 * q3 + c2 + g) & 15))] = r[u][q3];
#pragma unroll
  for (int u = 0; u < 2; ++u)
#pragma unroll
    for (int t = 0; t < 4; ++t) r[u][t] = S[u][ST * (g * 16 + ((4 * c2 + t + g) & 15))];
  // ---- F4 (final DFT-4) -> regs q4; mask q4 in {1,2}; I1 with 2 nonzero inputs
#pragma unroll
  for (int u = 0; u < 2; ++u) {
    dft4(r[u]);
    float2 V0 = r[u][0], V3 = r[u][3];
    r[u][0] = cadd(V0, V3);
    r[u][1] = make_float2(V0.x + V3.y, V0.y - V3.x);
    r[u][2] = csub(V0, V3);
    r[u][3] = make_float2(V0.x - V3.y, V0.y + V3.x);
    r[u][1] = cmulc(r[u][1], T.f3[0]);
    r[u][2] = cmulc(r[u][2], T.f3[1]);
    r[u][3] = cmulc(r[u][3], T.f3[2]);
  }
#pragma unroll
  for (int u = 0; u < 2; ++u)
#pragma unroll
    for (int j = 0; j < 4; ++j) S[u][ST * (g * 16 + ((4 * c2 + j + g) & 15))] = r[u][j];
#pragma unroll
  for (int u = 0; u < 2; ++u)
#pragma unroll
    for (int t = 0; t < 4; ++t) r[u][t] = S[u][ST * (g * 16 + ((4 * t + c2 + g) & 15))];
  // ---- I2 (inverse over q3) -> positions m = c2+4t; undo F2 twiddle
#pragma unroll
  for (int u = 0; u < 2; ++u) {
    idft4(r[u]);
    r[u][0] = cmulc(r[u][0], T.i2[0]);
    r[u][1] = cmulc(r[u][1], T.i2[1]);
    r[u][2] = cmulc(r[u][2], T.i2[2]);
    r[u][3] = cmulc(r[u][3], T.i2[3]);
  }
#pragma unroll
  for (int u = 0; u < 2; ++u)
#pragma unroll
    for (int t1 = 0; t1 < 4; ++t1) S[u][ST * (qq * 64 + q2r * 16 + ((c2 + 4 * t1 + 4 * q2r) & 15))] = r[u][t1];
#pragma unroll
  for (int u = 0; u < 2; ++u)
#pragma unroll
    for (int t = 0; t < 4; ++t) r[u][t] = S[u][ST * (qq * 64 + t * 16 + ((m + 4 * t) & 15))];
  // ---- I3 (inverse over q2) -> positions l' = m+16t; undo F1 twiddle
#pragma unroll
  for (int u = 0; u < 2; ++u) {
    idft4(r[u]);
    r[u][0] = cmulc(r[u][0], T.i3[0]);
    r[u][1] = cmulc(r[u][1], T.i3[1]);
    r[u][2] = cmulc(r[u][2], T.i3[2]);
    r[u][3] = cmulc(r[u][3], T.i3[3]);
  }
#pragma unroll
  for (int u = 0; u < 2; ++u)
#pragma unroll
    for (int t2 = 0; t2 < 4; ++t2) S[u][ST * (qq * 64 + m + 16 * t2)] = r[u][t2];
#pragma unroll
  for (int u = 0; u < 2; ++u)
#pragma unroll
    for (int t = 0; t < 4; ++t) r[u][t] = S[u][ST * (t * 64 + l)];
  // ---- I4 (inverse over q) -> x[l + 64t]
#pragma unroll
  for (int u = 0; u < 2; ++u) idft4(r[u]);
}

// Row pass: 8 lines/block (2 per wave), no barriers in transform
#define RPAD 4
__global__ __launch_bounds__(256)
void fft_rows_kernel(const float* __restrict__ y, float2* __restrict__ z1) {
  __shared__ float2 S[4][2][256 + RPAD];
  __shared__ float2 tw[256];
  const int tid = threadIdx.x;
  {
    float sn, cs;
    __sincosf(-2.f * PI_F * (float)tid / 256.f, &sn, &cs);
    tw[tid] = make_float2(cs, sn);
  }
  __syncthreads();
  const int wv = tid >> 6, l = tid & 63;
  TwSet T;
  load_tw(T, tw, l);
  const size_t row0 = ((size_t)blockIdx.x * 8 + wv * 2);
  float2 r[2][4];
#pragma unroll
  for (int u = 0; u < 2; ++u)
#pragma unroll
    for (int t = 0; t < 4; ++t) r[u][t] = make_float2(y[(row0 + u) * 256 + l + 64 * t], 0.f);
  fft_line2<1>(r, &S[wv][0][0], &S[wv][1][0], T, l);
#pragma unroll
  for (int u = 0; u < 2; ++u)
#pragma unroll
    for (int t = 0; t < 4; ++t)
      z1[(row0 + u) * 256 + l + 64 * t] =
          make_float2(r[u][t].x * (1.f / 256.f), r[u][t].y * (1.f / 256.f));
}

// Col pass: 16-col strip in LDS (stride 17), columns processed in pairs (2/wave-step)
#define CST 17
__global__ __launch_bounds__(256)
void fft_cols_kernel(const float2* __restrict__ z1, const float* __restrict__ yy,
                     float* __restrict__ out, const float* __restrict__ betaPtr) {
  __shared__ float2 strip[256 * CST];
  __shared__ float2 tw[256];
  const int tid = threadIdx.x;
  {
    float sn, cs;
    __sincosf(-2.f * PI_F * (float)tid / 256.f, &sn, &cs);
    tw[tid] = make_float2(cs, sn);
  }
  const int img = blockIdx.x >> 4;
  const int c0 = (blockIdx.x & 15) * 16;
  const size_t ibase = (size_t)img * 65536;
#pragma unroll
  for (int it = 0; it < 16; ++it) {
    int idx = it * 256 + tid;
    int rrow = idx >> 4, cc = idx & 15;
    strip[rrow * CST + cc] = z1[ibase + (size_t)rrow * 256 + c0 + cc];
  }
  __syncthreads();
  const int wv = tid >> 6, l = tid & 63;
  TwSet T;
  load_tw(T, tw, l);
  float2 r[2][4];
#pragma unroll
  for (int p = 0; p < 2; ++p) {
    const int c = wv * 4 + p * 2;
    float2* SA = strip + c;
    float2* SB = strip + c + 1;
#pragma unroll
    for (int t = 0; t < 4; ++t) {
      r[0][t] = SA[CST * (l + 64 * t)];
      r[1][t] = SB[CST * (l + 64 * t)];
    }
    fft_line2<CST>(r, SA, SB, T, l);
#pragma unroll
    for (int t = 0; t < 4; ++t) {
      float2 vA = r[0][t], vB = r[1][t];
      SA[CST * (l + 64 * t)].x = sqrtf(vA.x * vA.x + vA.y * vA.y) * (1.f / 256.f);
      SB[CST * (l + 64 * t)].x = sqrtf(vB.x * vB.x + vB.y * vB.y) * (1.f / 256.f);
    }
  }
  __syncthreads();
  const float beta = betaPtr[0];
  const float a1 = 1.f - 2.f * beta;
#pragma unroll
  for (int it = 0; it < 16; ++it) {
    int idx = it * 256 + tid;
    int rrow = idx >> 4, cc = idx & 15;
    size_t gi = ibase + (size_t)rrow * 256 + c0 + cc;
    out[gi] = beta * yy[gi] + a1 * strip[rrow * CST + cc].x;
  }
}

// ================= launch =================
extern "C" void kernel_launch(void* const* d_in, const int* in_sizes, int n_in,
                              void* d_out, int out_size, void* d_ws, size_t ws_size,
                              hipStream_t stream) {
  const float* x = (const float*)d_in[0];
  const float* wgt = (const float*)d_in[1];
  const float* beta = (const float*)d_in[2];
  float* out = (float*)d_out;

  const size_t wplane = (size_t)9 * 192 * 96;
  const size_t wbytes = (2 * wplane * sizeof(unsigned short) + 255) & ~(size_t)255;
  const size_t per_img = 65536ull * sizeof(float2);
  const int NIMG = 8 * 48;

  float2* z1;
  size_t z1_bytes;

  if (ws_size >= wbytes + per_img) {
    unsigned short* wpk = (unsigned short*)d_ws;
    z1 = (float2*)((char*)d_ws + wbytes);
    z1_bytes = ws_size - wbytes;
    prep_w<<<648, 256, 0, stream>>>(wgt, wpk);
    conv_mfma<<<dim3(2, 64, 8), 256, 0, stream>>>(x, wpk, out);
  } else {
    z1 = (float2*)d_ws;
    z1_bytes = ws_size;
    conv_ps_kernel<<<dim3(2, 8, 192), 256, 0, stream>>>(x, wgt, out);
  }

  int chunk = (int)(z1_bytes / per_img);
  if (chunk < 1) chunk = 1;
  if (chunk > NIMG) chunk = NIMG;
  for (int img0 = 0; img0 < NIMG; img0 += chunk) {
    int n = NIMG - img0;
    if (n > chunk) n = chunk;
    float* ych = out + (size_t)img0 * 65536;
    fft_rows_kernel<<<n * 32, 256, 0, stream>>>(ych, z1);
    fft_cols_kernel<<<n * 16, 256, 0, stream>>>(z1, ych, ych, beta);
  }
}

// Round 7
// 377.070 us; speedup vs baseline: 1.1894x; 1.0214x over previous
//
#include <hip/hip_runtime.h>
#include <math.h>

#define PI_F 3.14159265358979f

typedef __attribute__((ext_vector_type(8))) __bf16 bf16x8;
typedef __attribute__((ext_vector_type(4))) float f32x4;

__device__ __forceinline__ unsigned short f2bf_rne(float v) {
  union { float f; unsigned u; } c; c.f = v;
  unsigned u = c.u;
  return (unsigned short)((u + 0x7fffu + ((u >> 16) & 1u)) >> 16);
}
__device__ __forceinline__ float bfbits2f(unsigned short b) {
  union { unsigned u; float f; } c; c.u = ((unsigned)b) << 16; return c.f;
}
__device__ __forceinline__ unsigned pk2(float a, float b) {
  return (unsigned)f2bf_rne(a) | ((unsigned)f2bf_rne(b) << 16);
}

// ===== weight pre-split + pack: w[oc][ic][3][3] -> wpk[pos][oc][q]{hi[8],lo[8]} =====
__global__ void prep_w(const float* __restrict__ w, unsigned short* __restrict__ wpk) {
  int i = blockIdx.x * 256 + threadIdx.x;
  if (i >= 9 * 192 * 96) return;
  int pos = i / (192 * 96);
  int rem = i - pos * (192 * 96);
  int oc = rem / 96, ic = rem - oc * 96;
  float v = w[(size_t)rem * 9 + pos];
  unsigned short h = f2bf_rne(v);
  unsigned short l = f2bf_rne(v - bfbits2f(h));
  int q = ic >> 3, j = ic & 7;
  size_t base = ((size_t)(pos * 192 + oc) * 12 + q) * 16;
  wpk[base + j] = h;
  wpk[base + 8 + j] = l;
}

// ============ conv 3x3 implicit GEMM, H=2 rows/block, 3 ic-phases of 32 ============
// T14 async-STAGE split: phase p+1's global loads are issued into registers BEFORE
// phase p's compute (latency hides under ~2.7K cyc of MFMAs); converted and written
// to LDS only after the post-compute barrier. Loads cannot sink across
// __syncthreads(), so the compiler can't defeat the split (round-1 failure mode).
#define ICP 40

__global__ __launch_bounds__(256)
void conv_mfma(const float* __restrict__ x, const unsigned short* __restrict__ wpk,
               float* __restrict__ y) {
  __shared__ unsigned short patch[4 * 66 * ICP];
  const int tid  = threadIdx.x;
  const int wave = tid >> 6, lane = tid & 63;
  const int col  = lane & 15, quad = lane >> 4;
  const int w0 = blockIdx.x * 64;
  const int h0 = blockIdx.y * 2;                   // output rows h0, h0+1
  const int b  = blockIdx.z;
  const float* xb = x + (size_t)b * 96 * 128 * 128;

  f32x4 acc[2][3][4];
#pragma unroll
  for (int hh = 0; hh < 2; ++hh)
#pragma unroll
    for (int mt = 0; mt < 3; ++mt)
#pragma unroll
      for (int nt = 0; nt < 4; ++nt) acc[hh][mt][nt] = (f32x4)0.f;

  const int wbase = (48 * wave + col) * 192 + quad * 16;
  const int cg = tid & 15, pg = tid >> 4;
  // per-thread staging task geometry (constant across phases)
  const int sr  = pg & 3;                // staging row 0..3
  const int sic = (pg >> 2) * 2;         // staging local ic (even), 0..30
  const int sgr = h0 - 1 + sr;
  const int hside = tid & 1, hrr = (tid >> 1) & 3, hicl = tid >> 3;  // halo task
  const int hgr = h0 - 1 + hrr;
  const int hgc = hside ? (w0 + 64) : (w0 - 1);

  // staging register buffers (live across the compute loop for the next phase)
  float4 sv0[2], sv1[2];
  float hv;

  auto ISSUE = [&](int phase) {
    const int ic0 = phase * 32;
#pragma unroll
    for (int it = 0; it < 2; ++it) {
      // two 32-ic halves: it=0 -> ic sic, it=1 -> ic sic+16? No: tasks split by pg over
      // 4 rows x 16 ic-pairs = 64 tasks; 16 pg groups handle 4 tasks each via it*16+pg
      int pairid = it * 16 + pg;          // 0..31 (first 32 tasks)
      int r   = pairid & 3;
      int icl = (pairid >> 2) * 2;
      int gr  = h0 - 1 + r;
      const float* r0p = xb + (size_t)(ic0 + icl) * 16384 + gr * 128 + w0 + 4 * cg;
      sv0[it] = make_float4(0.f, 0.f, 0.f, 0.f);
      sv1[it] = sv0[it];
      if ((unsigned)gr < 128u) {
        sv0[it] = *(const float4*)(r0p);
        sv1[it] = *(const float4*)(r0p + 16384);
      }
    }
    hv = 0.f;
    if ((unsigned)hgr < 128u && (unsigned)hgc < 128u)
      hv = xb[(size_t)(ic0 + hicl) * 16384 + hgr * 128 + hgc];
  };
  // second half of the staging tasks (pairid 32..63) -- issued in the same call
  float4 tv0[2], tv1[2];
  auto ISSUE2 = [&](int phase) {
    const int ic0 = phase * 32;
#pragma unroll
    for (int it = 0; it < 2; ++it) {
      int pairid = 32 + it * 16 + pg;     // 32..63
      int r   = pairid & 3;
      int icl = (pairid >> 2) * 2;
      int gr  = h0 - 1 + r;
      const float* r0p = xb + (size_t)(ic0 + icl) * 16384 + gr * 128 + w0 + 4 * cg;
      tv0[it] = make_float4(0.f, 0.f, 0.f, 0.f);
      tv1[it] = tv0[it];
      if ((unsigned)gr < 128u) {
        tv0[it] = *(const float4*)(r0p);
        tv1[it] = *(const float4*)(r0p + 16384);
      }
    }
  };
  auto WRITE = [&]() {
#pragma unroll
    for (int it = 0; it < 2; ++it) {
      int pairid = it * 16 + pg;
      int r   = pairid & 3;
      int icl = (pairid >> 2) * 2;
      unsigned* pb = (unsigned*)&patch[(r * 66 + 1 + 4 * cg) * ICP + icl];
      pb[0]           = pk2(sv0[it].x, sv1[it].x);
      pb[ICP / 2]     = pk2(sv0[it].y, sv1[it].y);
      pb[ICP]         = pk2(sv0[it].z, sv1[it].z);
      pb[3 * ICP / 2] = pk2(sv0[it].w, sv1[it].w);
    }
#pragma unroll
    for (int it = 0; it < 2; ++it) {
      int pairid = 32 + it * 16 + pg;
      int r   = pairid & 3;
      int icl = (pairid >> 2) * 2;
      unsigned* pb = (unsigned*)&patch[(r * 66 + 1 + 4 * cg) * ICP + icl];
      pb[0]           = pk2(tv0[it].x, tv1[it].x);
      pb[ICP / 2]     = pk2(tv0[it].y, tv1[it].y);
      pb[ICP]         = pk2(tv0[it].z, tv1[it].z);
      pb[3 * ICP / 2] = pk2(tv0[it].w, tv1[it].w);
    }
    patch[(hrr * 66 + (hside ? 65 : 0)) * ICP + hicl] = f2bf_rne(hv);
  };

  ISSUE(0); ISSUE2(0);
  WRITE();
  __syncthreads();

  for (int phase = 0; phase < 3; ++phase) {
    // prefetch next phase's inputs into registers; latency hides under the pos loop
    if (phase < 2) { ISSUE(phase + 1); ISSUE2(phase + 1); }

#pragma unroll
    for (int pos = 0; pos < 9; ++pos) {
      const int dy = pos / 3, dx = pos - 3 * dy;
      bf16x8 ah[3], al[3];
#pragma unroll
      for (int mt = 0; mt < 3; ++mt) {
        const unsigned short* wp_ =
            wpk + wbase + (((pos * 192 + mt * 16) * 12 + phase * 4) * 16);
        ah[mt] = *(const bf16x8*)(wp_);
        al[mt] = *(const bf16x8*)(wp_ + 8);
      }
#pragma unroll
      for (int hh = 0; hh < 2; ++hh) {
        bf16x8 bfrag[4];
#pragma unroll
        for (int nt = 0; nt < 4; ++nt)
          bfrag[nt] = *(const bf16x8*)&patch[((dy + hh) * 66 + nt * 16 + col + dx) * ICP + quad * 8];
#pragma unroll
        for (int mt = 0; mt < 3; ++mt)
#pragma unroll
          for (int nt = 0; nt < 4; ++nt) {
            acc[hh][mt][nt] = __builtin_amdgcn_mfma_f32_16x16x32_bf16(ah[mt], bfrag[nt], acc[hh][mt][nt], 0, 0, 0);
            acc[hh][mt][nt] = __builtin_amdgcn_mfma_f32_16x16x32_bf16(al[mt], bfrag[nt], acc[hh][mt][nt], 0, 0, 0);
          }
      }
    }

    if (phase < 2) {
      __syncthreads();     // all waves done reading patch for this phase
      WRITE();             // convert + LDS-write the prefetched tile
      __syncthreads();     // tile visible before next compute
    }
  }

  float* yb = y + (size_t)b * 48 * 65536;
#pragma unroll
  for (int hh = 0; hh < 2; ++hh) {
    const int h = h0 + hh;
#pragma unroll
    for (int mt = 0; mt < 3; ++mt) {
#pragma unroll
      for (int p = 0; p < 2; ++p) {
        int r0 = 2 * p;
        int oc = 48 * wave + mt * 16 + quad * 4 + r0;
        int cq = oc >> 2, r2 = (oc >> 1) & 1;
        float* orow = yb + ((size_t)cq * 256 + 2 * h + r2) * 256;
#pragma unroll
        for (int nt = 0; nt < 4; ++nt) {
          int w = w0 + nt * 16 + col;
          *(float2*)&orow[2 * w] = make_float2(acc[hh][mt][nt][r0], acc[hh][mt][nt][r0 + 1]);
        }
      }
    }
  }
}

// ============ fallback fp32 conv ============
#define OCB 8
#define ICB 2
#define PSTRIDE 67
__global__ __launch_bounds__(256)
void conv_ps_kernel(const float* __restrict__ x, const float* __restrict__ wgt,
                    float* __restrict__ y) {
  __shared__ float wsh[OCB * 96 * 9];
  __shared__ float patch[ICB * 18 * PSTRIDE];
  const int tid = threadIdx.x;
  const int b = blockIdx.z / 24, ocg = blockIdx.z % 24;
  const int row0 = blockIdx.y * 16, col0 = blockIdx.x * 64;
  const int tx = tid & 15, ty = tid >> 4;
  for (int i = tid; i < OCB * 96 * 9; i += 256) wsh[i] = wgt[ocg * (OCB * 96 * 9) + i];
  float acc[OCB][4];
#pragma unroll
  for (int o = 0; o < OCB; ++o)
#pragma unroll
    for (int p = 0; p < 4; ++p) acc[o][p] = 0.f;
  const float* xb = x + (size_t)b * 96 * 128 * 128;
  for (int ic0 = 0; ic0 < 96; ic0 += ICB) {
    __syncthreads();
    for (int idx = tid; idx < ICB * 18 * 66; idx += 256) {
      int j = idx / (18 * 66), rem = idx - j * (18 * 66);
      int r = rem / 66, c = rem - r * 66;
      int gr = row0 - 1 + r, gc = col0 - 1 + c;
      float v = 0.f;
      if ((unsigned)gr < 128u && (unsigned)gc < 128u)
        v = xb[((size_t)(ic0 + j) * 128 + gr) * 128 + gc];
      patch[j * (18 * PSTRIDE) + r * PSTRIDE + c] = v;
    }
    __syncthreads();
#pragma unroll
    for (int j = 0; j < ICB; ++j) {
      float xr[3][6];
      const float* pp = &patch[j * (18 * PSTRIDE) + ty * PSTRIDE + tx * 4];
#pragma unroll
      for (int dy = 0; dy < 3; ++dy)
#pragma unroll
        for (int dx = 0; dx < 6; ++dx) xr[dy][dx] = pp[dy * PSTRIDE + dx];
#pragma unroll
      for (int o = 0; o < OCB; ++o) {
        const float* wp = &wsh[(o * 96 + ic0 + j) * 9];
#pragma unroll
        for (int p = 0; p < 4; ++p)
          acc[o][p] += wp[0] * xr[0][p] + wp[1] * xr[0][p + 1] + wp[2] * xr[0][p + 2]
                     + wp[3] * xr[1][p] + wp[4] * xr[1][p + 1] + wp[5] * xr[1][p + 2]
                     + wp[6] * xr[2][p] + wp[7] * xr[2][p + 1] + wp[8] * xr[2][p + 2];
      }
    }
  }
  const int h = row0 + ty;
#pragma unroll
  for (int o = 0; o < OCB; ++o) {
    int ocglob = ocg * OCB + o;
    int cq = ocglob >> 2, r2 = (ocglob >> 1) & 1, s2 = ocglob & 1;
    float* orow = y + (((size_t)b * 48 + cq) * 256 + (2 * h + r2)) * 256;
#pragma unroll
    for (int p = 0; p < 4; ++p) orow[2 * (col0 + tx * 4 + p) + s2] = acc[o][p];
  }
}

// ================= wave-synchronous register radix-4 FFT (256 = 4^4) =================
// Forward DIF: k = q + 4*q2 + 16*q3 + 64*q4. Mask k in [64,192) <=> q4 in {1,2}.
// 1-wide (round-4 form): 2-wide ILP was measured neutral (throughput-bound, not
// latency-bound) -- keep the simpler version.
__device__ __forceinline__ float2 cadd(float2 a, float2 b){return make_float2(a.x+b.x, a.y+b.y);}
__device__ __forceinline__ float2 csub(float2 a, float2 b){return make_float2(a.x-b.x, a.y-b.y);}
__device__ __forceinline__ float2 cmul(float2 a, float2 b){return make_float2(a.x*b.x-a.y*b.y, a.x*b.y+a.y*b.x);}
__device__ __forceinline__ float2 cmulc(float2 a, float2 b){return make_float2(a.x*b.x+a.y*b.y, a.y*b.x-a.x*b.y);}

__device__ __forceinline__ void dft4(float2 r[4]) {
  float2 e0 = cadd(r[0], r[2]), e1 = csub(r[0], r[2]);
  float2 o0 = cadd(r[1], r[3]), o1 = csub(r[1], r[3]);
  r[0] = cadd(e0, o0);
  r[2] = csub(e0, o0);
  r[1] = make_float2(e1.x + o1.y, e1.y - o1.x);
  r[3] = make_float2(e1.x - o1.y, e1.y + o1.x);
}
__device__ __forceinline__ void idft4(float2 r[4]) {
  float2 e0 = cadd(r[0], r[2]), e1 = csub(r[0], r[2]);
  float2 o0 = cadd(r[1], r[3]), o1 = csub(r[1], r[3]);
  r[0] = cadd(e0, o0);
  r[2] = csub(e0, o0);
  r[1] = make_float2(e1.x - o1.y, e1.y + o1.x);
  r[3] = make_float2(e1.x + o1.y, e1.y - o1.x);
}

struct TwSet {
  float2 f1[3], f2[3], f3[3], i2[4], i3[4];
};

__device__ __forceinline__ void load_tw(TwSet& T, const float2* __restrict__ tw, int l) {
  const int qq = l >> 4, m = l & 15, q2r = (l >> 2) & 3, c2 = l & 3;
  T.f1[0] = tw[l];
  T.f1[1] = tw[(2 * l) & 255];
  T.f1[2] = tw[(3 * l) & 255];
  T.f2[0] = tw[(4 * m) & 255];
  T.f2[1] = tw[(8 * m) & 255];
  T.f2[2] = tw[(12 * m) & 255];
  T.f3[0] = tw[(16 * c2) & 255];
  T.f3[1] = tw[(32 * c2) & 255];
  T.f3[2] = tw[(48 * c2) & 255];
  T.i2[0] = tw[(4 * c2 * q2r) & 255];
  T.i2[1] = tw[(4 * (c2 + 4) * q2r) & 255];
  T.i2[2] = tw[(4 * (c2 + 8) * q2r) & 255];
  T.i2[3] = tw[(4 * (c2 + 12) * q2r) & 255];
  T.i3[0] = tw[(m * qq) & 255];
  T.i3[1] = tw[((m + 16) * qq) & 255];
  T.i3[2] = tw[((m + 32) * qq) & 255];
  T.i3[3] = tw[((m + 48) * qq) & 255];
}

// r[t] in: x[l + 64t]; out: L[l + 64t] (unscaled). S = per-line LDS (element s at S[ST*s]).
template <int ST>
__device__ void fft_line_masked(float2 r[4], float2* __restrict__ S, const TwSet& T, int l) {
  const int qq = l >> 4, m = l & 15;
  const int g = l >> 2, q2r = (l >> 2) & 3, c2 = l & 3;
  // ---- F1 (stride 64) + twiddle w256^(l*q)
  dft4(r);
  r[1] = cmul(r[1], T.f1[0]);
  r[2] = cmul(r[2], T.f1[1]);
  r[3] = cmul(r[3], T.f1[2]);
  S[ST * l] = r[0];
  S[ST * (64 + l)] = r[1];
  S[ST * (128 + l)] = r[2];
  S[ST * (192 + l)] = r[3];
#pragma unroll
  for (int t = 0; t < 4; ++t) r[t] = S[ST * (qq * 64 + m + 16 * t)];
  // ---- F2 (stride 16 within 64) + w64^(m*q2)
  dft4(r);
  r[1] = cmul(r[1], T.f2[0]);
  r[2] = cmul(r[2], T.f2[1]);
  r[3] = cmul(r[3], T.f2[2]);
#pragma unroll
  for (int q2 = 0; q2 < 4; ++q2) S[ST * (qq * 64 + q2 * 16 + ((m + 4 * q2) & 15))] = r[q2];
#pragma unroll
  for (int t = 0; t < 4; ++t) r[t] = S[ST * (qq * 64 + q2r * 16 + ((c2 + 4 * t + 4 * q2r) & 15))];
  // ---- F3 (stride 4 within 16) + w16^(c*q3)
  dft4(r);
  r[1] = cmul(r[1], T.f3[0]);
  r[2] = cmul(r[2], T.f3[1]);
  r[3] = cmul(r[3], T.f3[2]);
#pragma unroll
  for (int q3 = 0; q3 < 4; ++q3) S[ST * (g * 16 + ((4 * q3 + c2 + g) & 15))] = r[q3];
#pragma unroll
  for (int t = 0; t < 4; ++t) r[t] = S[ST * (g * 16 + ((4 * c2 + t + g) & 15))];
  // ---- F4 (final DFT-4) -> regs q4; mask q4 in {1,2}; I1 with 2 nonzero inputs
  dft4(r);
  {
    float2 V0 = r[0], V3 = r[3];
    r[0] = cadd(V0, V3);
    r[1] = make_float2(V0.x + V3.y, V0.y - V3.x);   // V0 + (-i)V3
    r[2] = csub(V0, V3);
    r[3] = make_float2(V0.x - V3.y, V0.y + V3.x);   // V0 + (i)V3
  }
  // undo F3 twiddle (conj), reg index = c, lane q3 = c2
  r[1] = cmulc(r[1], T.f3[0]);
  r[2] = cmulc(r[2], T.f3[1]);
  r[3] = cmulc(r[3], T.f3[2]);
#pragma unroll
  for (int j = 0; j < 4; ++j) S[ST * (g * 16 + ((4 * c2 + j + g) & 15))] = r[j];
#pragma unroll
  for (int t = 0; t < 4; ++t) r[t] = S[ST * (g * 16 + ((4 * t + c2 + g) & 15))];
  // ---- I2 (inverse over q3) -> positions m = c2+4t; undo F2 twiddle
  idft4(r);
  r[0] = cmulc(r[0], T.i2[0]);
  r[1] = cmulc(r[1], T.i2[1]);
  r[2] = cmulc(r[2], T.i2[2]);
  r[3] = cmulc(r[3], T.i2[3]);
#pragma unroll
  for (int t1 = 0; t1 < 4; ++t1) S[ST * (qq * 64 + q2r * 16 + ((c2 + 4 * t1 + 4 * q2r) & 15))] = r[t1];
#pragma unroll
  for (int t = 0; t < 4; ++t) r[t] = S[ST * (qq * 64 + t * 16 + ((m + 4 * t) & 15))];
  // ---- I3 (inverse over q2) -> positions l' = m+16t; undo F1 twiddle
  idft4(r);
  r[0] = cmulc(r[0], T.i3[0]);
  r[1] = cmulc(r[1], T.i3[1]);
  r[2] = cmulc(r[2], T.i3[2]);
  r[3] = cmulc(r[3], T.i3[3]);
#pragma unroll
  for (int t2 = 0; t2 < 4; ++t2) S[ST * (qq * 64 + m + 16 * t2)] = r[t2];
#pragma unroll
  for (int t = 0; t < 4; ++t) r[t] = S[ST * (t * 64 + l)];
  // ---- I4 (inverse over q) -> x[l + 64t]
  idft4(r);
}

// Row pass: 4 lines/block (1 per wave), no barriers in transform
__global__ __launch_bounds__(256)
void fft_rows_kernel(const float* __restrict__ y, float2* __restrict__ z1) {
  __shared__ float2 S[4 * 256];
  __shared__ float2 tw[256];
  const int tid = threadIdx.x;
  {
    float sn, cs;
    __sincosf(-2.f * PI_F * (float)tid / 256.f, &sn, &cs);
    tw[tid] = make_float2(cs, sn);
  }
  __syncthreads();
  const int wv = tid >> 6, l = tid & 63;
  TwSet T;
  load_tw(T, tw, l);
  const size_t rowbase = ((size_t)blockIdx.x * 4 + wv) * 256;
  float2 r[4];
#pragma unroll
  for (int t = 0; t < 4; ++t) r[t] = make_float2(y[rowbase + l + 64 * t], 0.f);
  fft_line_masked<1>(r, S + wv * 256, T, l);
#pragma unroll
  for (int t = 0; t < 4; ++t)
    z1[rowbase + l + 64 * t] = make_float2(r[t].x * (1.f / 256.f), r[t].y * (1.f / 256.f));
}

// Col pass: 16-col strip in LDS (stride 17), in-place FFT per column, 4 cols/wave
#define CST 17
__global__ __launch_bounds__(256)
void fft_cols_kernel(const float2* __restrict__ z1, const float* __restrict__ yy,
                     float* __restrict__ out, const float* __restrict__ betaPtr) {
  __shared__ float2 strip[256 * CST];
  __shared__ float2 tw[256];
  const int tid = threadIdx.x;
  {
    float sn, cs;
    __sincosf(-2.f * PI_F * (float)tid / 256.f, &sn, &cs);
    tw[tid] = make_float2(cs, sn);
  }
  const int img = blockIdx.x >> 4;
  const int c0 = (blockIdx.x & 15) * 16;
  const size_t ibase = (size_t)img * 65536;
#pragma unroll
  for (int it = 0; it < 16; ++it) {
    int idx = it * 256 + tid;
    int rrow = idx >> 4, cc = idx & 15;
    strip[rrow * CST + cc] = z1[ibase + (size_t)rrow * 256 + c0 + cc];
  }
  __syncthreads();
  const int wv = tid >> 6, l = tid & 63;
  TwSet T;
  load_tw(T, tw, l);
  float2 r[4];
#pragma unroll
  for (int ci = 0; ci < 4; ++ci) {
    const int c = wv * 4 + ci;
    float2* Sc = strip + c;
#pragma unroll
    for (int t = 0; t < 4; ++t) r[t] = Sc[CST * (l + 64 * t)];
    fft_line_masked<CST>(r, Sc, T, l);
#pragma unroll
    for (int t = 0; t < 4; ++t) {
      float2 v = r[t];
      Sc[CST * (l + 64 * t)].x = sqrtf(v.x * v.x + v.y * v.y) * (1.f / 256.f);
    }
  }
  __syncthreads();
  const float beta = betaPtr[0];
  const float a1 = 1.f - 2.f * beta;
#pragma unroll
  for (int it = 0; it < 16; ++it) {
    int idx = it * 256 + tid;
    int rrow = idx >> 4, cc = idx & 15;
    size_t gi = ibase + (size_t)rrow * 256 + c0 + cc;
    out[gi] = beta * yy[gi] + a1 * strip[rrow * CST + cc].x;
  }
}

// ================= launch =================
extern "C" void kernel_launch(void* const* d_in, const int* in_sizes, int n_in,
                              void* d_out, int out_size, void* d_ws, size_t ws_size,
                              hipStream_t stream) {
  const float* x = (const float*)d_in[0];
  const float* wgt = (const float*)d_in[1];
  const float* beta = (const float*)d_in[2];
  float* out = (float*)d_out;

  const size_t wplane = (size_t)9 * 192 * 96;
  const size_t wbytes = (2 * wplane * sizeof(unsigned short) + 255) & ~(size_t)255;
  const size_t per_img = 65536ull * sizeof(float2);
  const int NIMG = 8 * 48;

  float2* z1;
  size_t z1_bytes;

  if (ws_size >= wbytes + per_img) {
    unsigned short* wpk = (unsigned short*)d_ws;
    z1 = (float2*)((char*)d_ws + wbytes);
    z1_bytes = ws_size - wbytes;
    prep_w<<<648, 256, 0, stream>>>(wgt, wpk);
    conv_mfma<<<dim3(2, 64, 8), 256, 0, stream>>>(x, wpk, out);
  } else {
    z1 = (float2*)d_ws;
    z1_bytes = ws_size;
    conv_ps_kernel<<<dim3(2, 8, 192), 256, 0, stream>>>(x, wgt, out);
  }

  int chunk = (int)(z1_bytes / per_img);
  if (chunk < 1) chunk = 1;
  if (chunk > NIMG) chunk = NIMG;
  for (int img0 = 0; img0 < NIMG; img0 += chunk) {
    int n = NIMG - img0;
    if (n > chunk) n = chunk;
    float* ych = out + (size_t)img0 * 65536;
    fft_rows_kernel<<<n * 64, 256, 0, stream>>>(ych, z1);
    fft_cols_kernel<<<n * 16, 256, 0, stream>>>(z1, ych, ych, beta);
  }
}

// Round 8
// 358.855 us; speedup vs baseline: 1.2497x; 1.0508x over previous
//
#include <hip/hip_runtime.h>
#include <hip/hip_fp16.h>
#include <math.h>

#define PI_F 3.14159265358979f

typedef __attribute__((ext_vector_type(8))) __bf16 bf16x8;
typedef __attribute__((ext_vector_type(4))) float f32x4;

__device__ __forceinline__ unsigned short f2bf_rne(float v) {
  union { float f; unsigned u; } c; c.f = v;
  unsigned u = c.u;
  return (unsigned short)((u + 0x7fffu + ((u >> 16) & 1u)) >> 16);
}
__device__ __forceinline__ float bfbits2f(unsigned short b) {
  union { unsigned u; float f; } c; c.u = ((unsigned)b) << 16; return c.f;
}
__device__ __forceinline__ unsigned pk2(float a, float b) {
  return (unsigned)f2bf_rne(a) | ((unsigned)f2bf_rne(b) << 16);
}

// ===== weight pre-split + pack: w[oc][ic][3][3] -> wpk[pos][oc][q]{hi[8],lo[8]} =====
__global__ void prep_w(const float* __restrict__ w, unsigned short* __restrict__ wpk) {
  int i = blockIdx.x * 256 + threadIdx.x;
  if (i >= 9 * 192 * 96) return;
  int pos = i / (192 * 96);
  int rem = i - pos * (192 * 96);
  int oc = rem / 96, ic = rem - oc * 96;
  float v = w[(size_t)rem * 9 + pos];
  unsigned short h = f2bf_rne(v);
  unsigned short l = f2bf_rne(v - bfbits2f(h));
  int q = ic >> 3, j = ic & 7;
  size_t base = ((size_t)(pos * 192 + oc) * 12 + q) * 16;
  wpk[base + j] = h;
  wpk[base + 8 + j] = l;
}

// ============ conv 3x3 implicit GEMM, H=2 rows/block, 3 ic-phases of 32 ============
// T14 async-STAGE split: phase p+1's global loads are issued into registers BEFORE
// phase p's compute; converted and LDS-written after the post-compute barrier.
#define ICP 40

__global__ __launch_bounds__(256)
void conv_mfma(const float* __restrict__ x, const unsigned short* __restrict__ wpk,
               float* __restrict__ y) {
  __shared__ unsigned short patch[4 * 66 * ICP];
  const int tid  = threadIdx.x;
  const int wave = tid >> 6, lane = tid & 63;
  const int col  = lane & 15, quad = lane >> 4;
  const int w0 = blockIdx.x * 64;
  const int h0 = blockIdx.y * 2;                   // output rows h0, h0+1
  const int b  = blockIdx.z;
  const float* xb = x + (size_t)b * 96 * 128 * 128;

  f32x4 acc[2][3][4];
#pragma unroll
  for (int hh = 0; hh < 2; ++hh)
#pragma unroll
    for (int mt = 0; mt < 3; ++mt)
#pragma unroll
      for (int nt = 0; nt < 4; ++nt) acc[hh][mt][nt] = (f32x4)0.f;

  const int wbase = (48 * wave + col) * 192 + quad * 16;
  const int cg = tid & 15, pg = tid >> 4;
  const int hside = tid & 1, hrr = (tid >> 1) & 3, hicl = tid >> 3;  // halo task
  const int hgr = h0 - 1 + hrr;
  const int hgc = hside ? (w0 + 64) : (w0 - 1);

  float4 sv0[2], sv1[2];
  float hv;
  auto ISSUE = [&](int phase) {
    const int ic0 = phase * 32;
#pragma unroll
    for (int it = 0; it < 2; ++it) {
      int pairid = it * 16 + pg;          // 0..31
      int r   = pairid & 3;
      int icl = (pairid >> 2) * 2;
      int gr  = h0 - 1 + r;
      const float* r0p = xb + (size_t)(ic0 + icl) * 16384 + gr * 128 + w0 + 4 * cg;
      sv0[it] = make_float4(0.f, 0.f, 0.f, 0.f);
      sv1[it] = sv0[it];
      if ((unsigned)gr < 128u) {
        sv0[it] = *(const float4*)(r0p);
        sv1[it] = *(const float4*)(r0p + 16384);
      }
    }
    hv = 0.f;
    if ((unsigned)hgr < 128u && (unsigned)hgc < 128u)
      hv = xb[(size_t)(ic0 + hicl) * 16384 + hgr * 128 + hgc];
  };
  float4 tv0[2], tv1[2];
  auto ISSUE2 = [&](int phase) {
    const int ic0 = phase * 32;
#pragma unroll
    for (int it = 0; it < 2; ++it) {
      int pairid = 32 + it * 16 + pg;     // 32..63
      int r   = pairid & 3;
      int icl = (pairid >> 2) * 2;
      int gr  = h0 - 1 + r;
      const float* r0p = xb + (size_t)(ic0 + icl) * 16384 + gr * 128 + w0 + 4 * cg;
      tv0[it] = make_float4(0.f, 0.f, 0.f, 0.f);
      tv1[it] = tv0[it];
      if ((unsigned)gr < 128u) {
        tv0[it] = *(const float4*)(r0p);
        tv1[it] = *(const float4*)(r0p + 16384);
      }
    }
  };
  auto WRITE = [&]() {
#pragma unroll
    for (int it = 0; it < 2; ++it) {
      int pairid = it * 16 + pg;
      int r   = pairid & 3;
      int icl = (pairid >> 2) * 2;
      unsigned* pb = (unsigned*)&patch[(r * 66 + 1 + 4 * cg) * ICP + icl];
      pb[0]           = pk2(sv0[it].x, sv1[it].x);
      pb[ICP / 2]     = pk2(sv0[it].y, sv1[it].y);
      pb[ICP]         = pk2(sv0[it].z, sv1[it].z);
      pb[3 * ICP / 2] = pk2(sv0[it].w, sv1[it].w);
    }
#pragma unroll
    for (int it = 0; it < 2; ++it) {
      int pairid = 32 + it * 16 + pg;
      int r   = pairid & 3;
      int icl = (pairid >> 2) * 2;
      unsigned* pb = (unsigned*)&patch[(r * 66 + 1 + 4 * cg) * ICP + icl];
      pb[0]           = pk2(tv0[it].x, tv1[it].x);
      pb[ICP / 2]     = pk2(tv0[it].y, tv1[it].y);
      pb[ICP]         = pk2(tv0[it].z, tv1[it].z);
      pb[3 * ICP / 2] = pk2(tv0[it].w, tv1[it].w);
    }
    patch[(hrr * 66 + (hside ? 65 : 0)) * ICP + hicl] = f2bf_rne(hv);
  };

  ISSUE(0); ISSUE2(0);
  WRITE();
  __syncthreads();

  for (int phase = 0; phase < 3; ++phase) {
    if (phase < 2) { ISSUE(phase + 1); ISSUE2(phase + 1); }

#pragma unroll
    for (int pos = 0; pos < 9; ++pos) {
      const int dy = pos / 3, dx = pos - 3 * dy;
      bf16x8 ah[3], al[3];
#pragma unroll
      for (int mt = 0; mt < 3; ++mt) {
        const unsigned short* wp_ =
            wpk + wbase + (((pos * 192 + mt * 16) * 12 + phase * 4) * 16);
        ah[mt] = *(const bf16x8*)(wp_);
        al[mt] = *(const bf16x8*)(wp_ + 8);
      }
#pragma unroll
      for (int hh = 0; hh < 2; ++hh) {
        bf16x8 bfrag[4];
#pragma unroll
        for (int nt = 0; nt < 4; ++nt)
          bfrag[nt] = *(const bf16x8*)&patch[((dy + hh) * 66 + nt * 16 + col + dx) * ICP + quad * 8];
#pragma unroll
        for (int mt = 0; mt < 3; ++mt)
#pragma unroll
          for (int nt = 0; nt < 4; ++nt) {
            acc[hh][mt][nt] = __builtin_amdgcn_mfma_f32_16x16x32_bf16(ah[mt], bfrag[nt], acc[hh][mt][nt], 0, 0, 0);
            acc[hh][mt][nt] = __builtin_amdgcn_mfma_f32_16x16x32_bf16(al[mt], bfrag[nt], acc[hh][mt][nt], 0, 0, 0);
          }
      }
    }

    if (phase < 2) {
      __syncthreads();
      WRITE();
      __syncthreads();
    }
  }

  float* yb = y + (size_t)b * 48 * 65536;
#pragma unroll
  for (int hh = 0; hh < 2; ++hh) {
    const int h = h0 + hh;
#pragma unroll
    for (int mt = 0; mt < 3; ++mt) {
#pragma unroll
      for (int p = 0; p < 2; ++p) {
        int r0 = 2 * p;
        int oc = 48 * wave + mt * 16 + quad * 4 + r0;
        int cq = oc >> 2, r2 = (oc >> 1) & 1;
        float* orow = yb + ((size_t)cq * 256 + 2 * h + r2) * 256;
#pragma unroll
        for (int nt = 0; nt < 4; ++nt) {
          int w = w0 + nt * 16 + col;
          *(float2*)&orow[2 * w] = make_float2(acc[hh][mt][nt][r0], acc[hh][mt][nt][r0 + 1]);
        }
      }
    }
  }
}

// ============ fallback fp32 conv ============
#define OCB 8
#define ICB 2
#define PSTRIDE 67
__global__ __launch_bounds__(256)
void conv_ps_kernel(const float* __restrict__ x, const float* __restrict__ wgt,
                    float* __restrict__ y) {
  __shared__ float wsh[OCB * 96 * 9];
  __shared__ float patch[ICB * 18 * PSTRIDE];
  const int tid = threadIdx.x;
  const int b = blockIdx.z / 24, ocg = blockIdx.z % 24;
  const int row0 = blockIdx.y * 16, col0 = blockIdx.x * 64;
  const int tx = tid & 15, ty = tid >> 4;
  for (int i = tid; i < OCB * 96 * 9; i += 256) wsh[i] = wgt[ocg * (OCB * 96 * 9) + i];
  float acc[OCB][4];
#pragma unroll
  for (int o = 0; o < OCB; ++o)
#pragma unroll
    for (int p = 0; p < 4; ++p) acc[o][p] = 0.f;
  const float* xb = x + (size_t)b * 96 * 128 * 128;
  for (int ic0 = 0; ic0 < 96; ic0 += ICB) {
    __syncthreads();
    for (int idx = tid; idx < ICB * 18 * 66; idx += 256) {
      int j = idx / (18 * 66), rem = idx - j * (18 * 66);
      int r = rem / 66, c = rem - r * 66;
      int gr = row0 - 1 + r, gc = col0 - 1 + c;
      float v = 0.f;
      if ((unsigned)gr < 128u && (unsigned)gc < 128u)
        v = xb[((size_t)(ic0 + j) * 128 + gr) * 128 + gc];
      patch[j * (18 * PSTRIDE) + r * PSTRIDE + c] = v;
    }
    __syncthreads();
#pragma unroll
    for (int j = 0; j < ICB; ++j) {
      float xr[3][6];
      const float* pp = &patch[j * (18 * PSTRIDE) + ty * PSTRIDE + tx * 4];
#pragma unroll
      for (int dy = 0; dy < 3; ++dy)
#pragma unroll
        for (int dx = 0; dx < 6; ++dx) xr[dy][dx] = pp[dy * PSTRIDE + dx];
#pragma unroll
      for (int o = 0; o < OCB; ++o) {
        const float* wp = &wsh[(o * 96 + ic0 + j) * 9];
#pragma unroll
        for (int p = 0; p < 4; ++p)
          acc[o][p] += wp[0] * xr[0][p] + wp[1] * xr[0][p + 1] + wp[2] * xr[0][p + 2]
                     + wp[3] * xr[1][p] + wp[4] * xr[1][p + 1] + wp[5] * xr[1][p + 2]
                     + wp[6] * xr[2][p] + wp[7] * xr[2][p + 1] + wp[8] * xr[2][p + 2];
      }
    }
  }
  const int h = row0 + ty;
#pragma unroll
  for (int o = 0; o < OCB; ++o) {
    int ocglob = ocg * OCB + o;
    int cq = ocglob >> 2, r2 = (ocglob >> 1) & 1, s2 = ocglob & 1;
    float* orow = y + (((size_t)b * 48 + cq) * 256 + (2 * h + r2)) * 256;
#pragma unroll
    for (int p = 0; p < 4; ++p) orow[2 * (col0 + tx * 4 + p) + s2] = acc[o][p];
  }
}

// ================= wave-synchronous register radix-4 FFT (256 = 4^4) =================
// z1 intermediate stored as fp16 complex (half2, 4B): halves z1 HBM write+read and
// shrinks the FFT working set (z1 98.3MB + y 98.3MB < 256MB L3) so the z1 re-read
// is largely L3-served. LDS/transform math unchanged (fp32).
__device__ __forceinline__ float2 cadd(float2 a, float2 b){return make_float2(a.x+b.x, a.y+b.y);}
__device__ __forceinline__ float2 csub(float2 a, float2 b){return make_float2(a.x-b.x, a.y-b.y);}
__device__ __forceinline__ float2 cmul(float2 a, float2 b){return make_float2(a.x*b.x-a.y*b.y, a.x*b.y+a.y*b.x);}
__device__ __forceinline__ float2 cmulc(float2 a, float2 b){return make_float2(a.x*b.x+a.y*b.y, a.y*b.x-a.x*b.y);}

__device__ __forceinline__ void dft4(float2 r[4]) {
  float2 e0 = cadd(r[0], r[2]), e1 = csub(r[0], r[2]);
  float2 o0 = cadd(r[1], r[3]), o1 = csub(r[1], r[3]);
  r[0] = cadd(e0, o0);
  r[2] = csub(e0, o0);
  r[1] = make_float2(e1.x + o1.y, e1.y - o1.x);
  r[3] = make_float2(e1.x - o1.y, e1.y + o1.x);
}
__device__ __forceinline__ void idft4(float2 r[4]) {
  float2 e0 = cadd(r[0], r[2]), e1 = csub(r[0], r[2]);
  float2 o0 = cadd(r[1], r[3]), o1 = csub(r[1], r[3]);
  r[0] = cadd(e0, o0);
  r[2] = csub(e0, o0);
  r[1] = make_float2(e1.x - o1.y, e1.y + o1.x);
  r[3] = make_float2(e1.x + o1.y, e1.y - o1.x);
}

struct TwSet {
  float2 f1[3], f2[3], f3[3], i2[4], i3[4];
};

__device__ __forceinline__ void load_tw(TwSet& T, const float2* __restrict__ tw, int l) {
  const int qq = l >> 4, m = l & 15, q2r = (l >> 2) & 3, c2 = l & 3;
  T.f1[0] = tw[l];
  T.f1[1] = tw[(2 * l) & 255];
  T.f1[2] = tw[(3 * l) & 255];
  T.f2[0] = tw[(4 * m) & 255];
  T.f2[1] = tw[(8 * m) & 255];
  T.f2[2] = tw[(12 * m) & 255];
  T.f3[0] = tw[(16 * c2) & 255];
  T.f3[1] = tw[(32 * c2) & 255];
  T.f3[2] = tw[(48 * c2) & 255];
  T.i2[0] = tw[(4 * c2 * q2r) & 255];
  T.i2[1] = tw[(4 * (c2 + 4) * q2r) & 255];
  T.i2[2] = tw[(4 * (c2 + 8) * q2r) & 255];
  T.i2[3] = tw[(4 * (c2 + 12) * q2r) & 255];
  T.i3[0] = tw[(m * qq) & 255];
  T.i3[1] = tw[((m + 16) * qq) & 255];
  T.i3[2] = tw[((m + 32) * qq) & 255];
  T.i3[3] = tw[((m + 48) * qq) & 255];
}

// r[t] in: x[l + 64t]; out: L[l + 64t] (unscaled). S = per-line LDS (element s at S[ST*s]).
template <int ST>
__device__ void fft_line_masked(float2 r[4], float2* __restrict__ S, const TwSet& T, int l) {
  const int qq = l >> 4, m = l & 15;
  const int g = l >> 2, q2r = (l >> 2) & 3, c2 = l & 3;
  // ---- F1 (stride 64) + twiddle w256^(l*q)
  dft4(r);
  r[1] = cmul(r[1], T.f1[0]);
  r[2] = cmul(r[2], T.f1[1]);
  r[3] = cmul(r[3], T.f1[2]);
  S[ST * l] = r[0];
  S[ST * (64 + l)] = r[1];
  S[ST * (128 + l)] = r[2];
  S[ST * (192 + l)] = r[3];
#pragma unroll
  for (int t = 0; t < 4; ++t) r[t] = S[ST * (qq * 64 + m + 16 * t)];
  // ---- F2 (stride 16 within 64) + w64^(m*q2)
  dft4(r);
  r[1] = cmul(r[1], T.f2[0]);
  r[2] = cmul(r[2], T.f2[1]);
  r[3] = cmul(r[3], T.f2[2]);
#pragma unroll
  for (int q2 = 0; q2 < 4; ++q2) S[ST * (qq * 64 + q2 * 16 + ((m + 4 * q2) & 15))] = r[q2];
#pragma unroll
  for (int t = 0; t < 4; ++t) r[t] = S[ST * (qq * 64 + q2r * 16 + ((c2 + 4 * t + 4 * q2r) & 15))];
  // ---- F3 (stride 4 within 16) + w16^(c*q3)
  dft4(r);
  r[1] = cmul(r[1], T.f3[0]);
  r[2] = cmul(r[2], T.f3[1]);
  r[3] = cmul(r[3], T.f3[2]);
#pragma unroll
  for (int q3 = 0; q3 < 4; ++q3) S[ST * (g * 16 + ((4 * q3 + c2 + g) & 15))] = r[q3];
#pragma unroll
  for (int t = 0; t < 4; ++t) r[t] = S[ST * (g * 16 + ((4 * c2 + t + g) & 15))];
  // ---- F4 (final DFT-4) -> regs q4; mask q4 in {1,2}; I1 with 2 nonzero inputs
  dft4(r);
  {
    float2 V0 = r[0], V3 = r[3];
    r[0] = cadd(V0, V3);
    r[1] = make_float2(V0.x + V3.y, V0.y - V3.x);   // V0 + (-i)V3
    r[2] = csub(V0, V3);
    r[3] = make_float2(V0.x - V3.y, V0.y + V3.x);   // V0 + (i)V3
  }
  // undo F3 twiddle (conj), reg index = c, lane q3 = c2
  r[1] = cmulc(r[1], T.f3[0]);
  r[2] = cmulc(r[2], T.f3[1]);
  r[3] = cmulc(r[3], T.f3[2]);
#pragma unroll
  for (int j = 0; j < 4; ++j) S[ST * (g * 16 + ((4 * c2 + j + g) & 15))] = r[j];
#pragma unroll
  for (int t = 0; t < 4; ++t) r[t] = S[ST * (g * 16 + ((4 * t + c2 + g) & 15))];
  // ---- I2 (inverse over q3) -> positions m = c2+4t; undo F2 twiddle
  idft4(r);
  r[0] = cmulc(r[0], T.i2[0]);
  r[1] = cmulc(r[1], T.i2[1]);
  r[2] = cmulc(r[2], T.i2[2]);
  r[3] = cmulc(r[3], T.i2[3]);
#pragma unroll
  for (int t1 = 0; t1 < 4; ++t1) S[ST * (qq * 64 + q2r * 16 + ((c2 + 4 * t1 + 4 * q2r) & 15))] = r[t1];
#pragma unroll
  for (int t = 0; t < 4; ++t) r[t] = S[ST * (qq * 64 + t * 16 + ((m + 4 * t) & 15))];
  // ---- I3 (inverse over q2) -> positions l' = m+16t; undo F1 twiddle
  idft4(r);
  r[0] = cmulc(r[0], T.i3[0]);
  r[1] = cmulc(r[1], T.i3[1]);
  r[2] = cmulc(r[2], T.i3[2]);
  r[3] = cmulc(r[3], T.i3[3]);
#pragma unroll
  for (int t2 = 0; t2 < 4; ++t2) S[ST * (qq * 64 + m + 16 * t2)] = r[t2];
#pragma unroll
  for (int t = 0; t < 4; ++t) r[t] = S[ST * (t * 64 + l)];
  // ---- I4 (inverse over q) -> x[l + 64t]
  idft4(r);
}

// Row pass: 4 lines/block (1 per wave); z1 out = packed half2
__global__ __launch_bounds__(256)
void fft_rows_kernel(const float* __restrict__ y, unsigned* __restrict__ z1) {
  __shared__ float2 S[4 * 256];
  __shared__ float2 tw[256];
  const int tid = threadIdx.x;
  {
    float sn, cs;
    __sincosf(-2.f * PI_F * (float)tid / 256.f, &sn, &cs);
    tw[tid] = make_float2(cs, sn);
  }
  __syncthreads();
  const int wv = tid >> 6, l = tid & 63;
  TwSet T;
  load_tw(T, tw, l);
  const size_t rowbase = ((size_t)blockIdx.x * 4 + wv) * 256;
  float2 r[4];
#pragma unroll
  for (int t = 0; t < 4; ++t) r[t] = make_float2(y[rowbase + l + 64 * t], 0.f);
  fft_line_masked<1>(r, S + wv * 256, T, l);
#pragma unroll
  for (int t = 0; t < 4; ++t) {
    __half2 h = __floats2half2_rn(r[t].x * (1.f / 256.f), r[t].y * (1.f / 256.f));
    z1[rowbase + l + 64 * t] = *reinterpret_cast<unsigned*>(&h);
  }
}

// Col pass: 16-col strip in LDS (stride 17); z1 in = packed half2, unpack to fp32
#define CST 17
__global__ __launch_bounds__(256)
void fft_cols_kernel(const unsigned* __restrict__ z1, const float* __restrict__ yy,
                     float* __restrict__ out, const float* __restrict__ betaPtr) {
  __shared__ float2 strip[256 * CST];
  __shared__ float2 tw[256];
  const int tid = threadIdx.x;
  {
    float sn, cs;
    __sincosf(-2.f * PI_F * (float)tid / 256.f, &sn, &cs);
    tw[tid] = make_float2(cs, sn);
  }
  const int img = blockIdx.x >> 4;
  const int c0 = (blockIdx.x & 15) * 16;
  const size_t ibase = (size_t)img * 65536;
#pragma unroll
  for (int it = 0; it < 16; ++it) {
    int idx = it * 256 + tid;
    int rrow = idx >> 4, cc = idx & 15;
    unsigned u = z1[ibase + (size_t)rrow * 256 + c0 + cc];
    __half2 h = *reinterpret_cast<__half2*>(&u);
    strip[rrow * CST + cc] = __half22float2(h);
  }
  __syncthreads();
  const int wv = tid >> 6, l = tid & 63;
  TwSet T;
  load_tw(T, tw, l);
  float2 r[4];
#pragma unroll
  for (int ci = 0; ci < 4; ++ci) {
    const int c = wv * 4 + ci;
    float2* Sc = strip + c;
#pragma unroll
    for (int t = 0; t < 4; ++t) r[t] = Sc[CST * (l + 64 * t)];
    fft_line_masked<CST>(r, Sc, T, l);
#pragma unroll
    for (int t = 0; t < 4; ++t) {
      float2 v = r[t];
      Sc[CST * (l + 64 * t)].x = sqrtf(v.x * v.x + v.y * v.y) * (1.f / 256.f);
    }
  }
  __syncthreads();
  const float beta = betaPtr[0];
  const float a1 = 1.f - 2.f * beta;
#pragma unroll
  for (int it = 0; it < 16; ++it) {
    int idx = it * 256 + tid;
    int rrow = idx >> 4, cc = idx & 15;
    size_t gi = ibase + (size_t)rrow * 256 + c0 + cc;
    out[gi] = beta * yy[gi] + a1 * strip[rrow * CST + cc].x;
  }
}

// ================= launch =================
extern "C" void kernel_launch(void* const* d_in, const int* in_sizes, int n_in,
                              void* d_out, int out_size, void* d_ws, size_t ws_size,
                              hipStream_t stream) {
  const float* x = (const float*)d_in[0];
  const float* wgt = (const float*)d_in[1];
  const float* beta = (const float*)d_in[2];
  float* out = (float*)d_out;

  const size_t wplane = (size_t)9 * 192 * 96;
  const size_t wbytes = (2 * wplane * sizeof(unsigned short) + 255) & ~(size_t)255;
  const size_t per_img = 65536ull * sizeof(unsigned);   // half2 z1: 4B/element
  const int NIMG = 8 * 48;

  unsigned* z1;
  size_t z1_bytes;

  if (ws_size >= wbytes + per_img) {
    unsigned short* wpk = (unsigned short*)d_ws;
    z1 = (unsigned*)((char*)d_ws + wbytes);
    z1_bytes = ws_size - wbytes;
    prep_w<<<648, 256, 0, stream>>>(wgt, wpk);
    conv_mfma<<<dim3(2, 64, 8), 256, 0, stream>>>(x, wpk, out);
  } else {
    z1 = (unsigned*)d_ws;
    z1_bytes = ws_size;
    conv_ps_kernel<<<dim3(2, 8, 192), 256, 0, stream>>>(x, wgt, out);
  }

  int chunk = (int)(z1_bytes / per_img);
  if (chunk < 1) chunk = 1;
  if (chunk > NIMG) chunk = NIMG;
  for (int img0 = 0; img0 < NIMG; img0 += chunk) {
    int n = NIMG - img0;
    if (n > chunk) n = chunk;
    float* ych = out + (size_t)img0 * 65536;
    fft_rows_kernel<<<n * 64, 256, 0, stream>>>(ych, z1);
    fft_cols_kernel<<<n * 16, 256, 0, stream>>>(z1, ych, ych, beta);
  }
}